// Round 8
// baseline (383.318 us; speedup 1.0000x reference)
//
#include <hip/hip_runtime.h>
#include <hip/hip_bf16.h>

typedef __attribute__((ext_vector_type(4))) float f32x4;
typedef __attribute__((ext_vector_type(8))) short s16x8;
typedef unsigned int u32;
typedef unsigned short u16;

#define GLDS16(gp, lp) __builtin_amdgcn_global_load_lds(                         \
    (const __attribute__((address_space(1))) u32*)(gp),                          \
    (__attribute__((address_space(3))) u32*)(lp), 16, 0, 0)
#define VMCNT10 asm volatile("s_waitcnt vmcnt(10)" ::: "memory")
#define VMCNT6 asm volatile("s_waitcnt vmcnt(6)" ::: "memory")
#define VMCNT4 asm volatile("s_waitcnt vmcnt(4)" ::: "memory")
#define VMCNT0 asm volatile("s_waitcnt vmcnt(0)" ::: "memory")
#define LGKM8  asm volatile("s_waitcnt lgkmcnt(8)" ::: "memory")
#define LGKM0  asm volatile("s_waitcnt lgkmcnt(0)" ::: "memory")
#define SBAR   __builtin_amdgcn_sched_barrier(0)

__device__ __forceinline__ u16 f2bf(float f) {
    u32 u = __builtin_bit_cast(u32, f);
    u32 r = (u + 0x7FFFu + ((u >> 16) & 1u)) >> 16;
    return (u16)r;
}
__device__ __forceinline__ float bf2f(u16 h) {
    u32 u = ((u32)h) << 16;
    return __builtin_bit_cast(float, u);
}

// ---------------- fused prep: x cast + 4 weight transposes, one launch ----------
// blocks [0,8192): conv f32->bf16 of x (float4)
// blocks [8192,13312): wtrans 32k x 128n tiles, float4 reads
__global__ __launch_bounds__(256) void prep(const float4* __restrict__ x,
                                            ushort4* __restrict__ xb4,
                                            const float* __restrict__ wq,
                                            const float* __restrict__ wk,
                                            const float* __restrict__ wv,
                                            const float* __restrict__ wo,
                                            u16* __restrict__ WT,
                                            u16* __restrict__ woT) {
    __shared__ float tile[32][132];  // pad 4: benign 4-way on scalar access
    int bid = blockIdx.x;
    if (bid < 8192) {
        int i = bid * 256 + threadIdx.x;
        float4 v = x[i];
        ushort4 o;
        o.x = f2bf(v.x); o.y = f2bf(v.y); o.z = f2bf(v.z); o.w = f2bf(v.w);
        xb4[i] = o;
        return;
    }
    bid -= 8192;
    const float* src;
    u16* dst;
    int N, bx, by;
    if (bid < 1536)      { src = wq; dst = WT;                         N = 3072; bx = bid % 24; by = bid / 24; }
    else if (bid < 3072) { bid -= 1536; src = wk; dst = WT + (size_t)3072 * 2048; N = 3072; bx = bid % 24; by = bid / 24; }
    else if (bid < 4096) { bid -= 3072; src = wv; dst = WT + (size_t)6144 * 2048; N = 2048; bx = bid % 16; by = bid / 16; }
    else                 { bid -= 4096; src = wo; dst = woT;           N = 2048; bx = bid % 16; by = bid / 16; }
    int n0 = bx * 128, k0 = by * 32;
    int nf = threadIdx.x & 31, kr = threadIdx.x >> 5;  // 32 float4-cols x 8 rows
#pragma unroll
    for (int i = 0; i < 4; ++i) {
        int row = kr + i * 8;
        float4 v = *(const float4*)&src[(size_t)(k0 + row) * N + n0 + 4 * nf];
        tile[row][4 * nf + 0] = v.x;
        tile[row][4 * nf + 1] = v.y;
        tile[row][4 * nf + 2] = v.z;
        tile[row][4 * nf + 3] = v.w;
    }
    __syncthreads();
    int kk = threadIdx.x & 31, nr0 = threadIdx.x >> 5;  // 32 k x 8 n-rows/pass
#pragma unroll
    for (int i = 0; i < 16; ++i) {
        int n = nr0 + i * 8;
        dst[(size_t)(n0 + n) * 2048 + k0 + kk] = f2bf(tile[kk][n]);
    }
}

// ---------------- fused QKV GEMM: m201 8-phase template, BK=64, 2x2-half dbuf ----
// Epilogue: head-pack Q/K into [BH][S][192], V plain [4096][2048].
// NOTE (R4): no transcendentals here. NOTE (R6): no scattered V-transpose here.
__global__ __launch_bounds__(512, 2) void gemm_qkv(const u16* __restrict__ A,
                                                   const u16* __restrict__ W,
                                                   u16* __restrict__ Qh,
                                                   u16* __restrict__ Kh,
                                                   u16* __restrict__ Vn) {
    __shared__ __align__(16) u16 S[2][2][2][128 * 64];  // [mat][dbuf][half] 128 KiB
    const int tid = threadIdx.x, lane = tid & 63, wid = tid >> 6;
    const int l15 = lane & 15, l4 = lane >> 4;
    const int id = blockIdx.x;
    const int nt = ((id & 7) << 2) + ((id >> 3) & 3);
    const int mt = id >> 5;
    const int bm0 = mt << 8, bn0 = nt << 8;
    const int wr = wid >> 2, wc = wid & 3;  // 2M x 4N
    f32x4 acc[8][4] = {};

    auto stageH = [&](int mat, int tt, int h) {
        const int kc = tt << 6, p = tt & 1;
        const u16* G = mat ? W : A;
        const int rbase = (mat ? bn0 : bm0) + (h << 7);
        u16* Ld = S[mat][p][h];
#pragma unroll
        for (int j = 0; j < 2; ++j) {
            int c = j * 512 + tid;
            int row = c >> 3, ch = c & 7;
            int cs = ch ^ (row & 7);
            GLDS16(G + (size_t)(rbase + row) * 2048 + kc + cs * 8,
                   (char*)Ld + (j * 512 + wid * 64) * 16);
        }
    };

    s16x8 af[2][2], bfr[4][2];

#define RDA(P, I)                                                              \
    _Pragma("unroll") for (int mm = 0; mm < 2; ++mm)                           \
    _Pragma("unroll") for (int kk = 0; kk < 2; ++kk) {                         \
        int r7 = ((I) * 2 + mm) * 16 + l15;                                    \
        int byt = r7 * 128 + (((kk * 4 + l4) ^ (r7 & 7)) << 4);                \
        af[mm][kk] = *(const s16x8*)((const char*)S[0][P][wr] + byt);          \
    }
#define RDB(P)                                                                 \
    _Pragma("unroll") for (int n = 0; n < 4; ++n)                              \
    _Pragma("unroll") for (int kk = 0; kk < 2; ++kk) {                         \
        int r7 = (wc & 1) * 64 + n * 16 + l15;                                 \
        int byt = r7 * 128 + (((kk * 4 + l4) ^ (r7 & 7)) << 4);                \
        bfr[n][kk] = *(const s16x8*)((const char*)S[1][P][wc >> 1] + byt);     \
    }
#define MF(I)                                                                  \
    __builtin_amdgcn_s_setprio(1);                                             \
    _Pragma("unroll") for (int mm = 0; mm < 2; ++mm)                           \
    _Pragma("unroll") for (int n = 0; n < 4; ++n)                              \
    _Pragma("unroll") for (int kk = 0; kk < 2; ++kk)                           \
        acc[(I) * 2 + mm][n] = __builtin_amdgcn_mfma_f32_16x16x32_bf16(        \
            af[mm][kk], bfr[n][kk], acc[(I) * 2 + mm][n], 0, 0, 0);            \
    __builtin_amdgcn_s_setprio(0);

    stageH(0, 0, 0); stageH(0, 0, 1); stageH(1, 0, 0); stageH(1, 0, 1);
    stageH(0, 1, 0); stageH(0, 1, 1);
    VMCNT4;
    __builtin_amdgcn_s_barrier();
    SBAR;

    for (int t = 0; t < 32; ++t) {
        const int p = t & 1;
        RDB(p); RDA(p, 0);
        if (t == 0) stageH(1, 1, 0);
        else if (t < 31) stageH(0, t + 1, 0);
        LGKM8; SBAR;
        __builtin_amdgcn_s_barrier();
        LGKM0; SBAR;
        MF(0); SBAR;
        __builtin_amdgcn_s_barrier();
        RDA(p, 1);
        if (t == 0) stageH(1, 1, 1);
        else if (t < 31) stageH(0, t + 1, 1);
        __builtin_amdgcn_s_barrier();
        LGKM0; SBAR;
        MF(1); SBAR;
        __builtin_amdgcn_s_barrier();
        RDA(p, 2);
        if (t < 30) stageH(1, t + 2, 0);
        __builtin_amdgcn_s_barrier();
        LGKM0; SBAR;
        MF(2); SBAR;
        __builtin_amdgcn_s_barrier();
        RDA(p, 3);
        if (t < 30) stageH(1, t + 2, 1);
        __builtin_amdgcn_s_barrier();
        LGKM0; SBAR;
        MF(3); SBAR;
        if (t < 31) {
            if (t < 30) { VMCNT4; } else { VMCNT0; }
            SBAR;
        }
        __builtin_amdgcn_s_barrier();
    }
#undef RDA
#undef RDB
#undef MF

    // epilogue
#pragma unroll
    for (int m = 0; m < 8; ++m)
#pragma unroll
        for (int n = 0; n < 4; ++n)
#pragma unroll
            for (int r = 0; r < 4; ++r) {
                int row = bm0 + wr * 128 + m * 16 + l4 * 4 + r;
                int c = bn0 + wc * 64 + n * 16 + l15;
                float v = acc[m][n][r];
                if (bn0 >= 6144) {
                    Vn[(size_t)row * 2048 + (c - 6144)] = f2bf(v);
                } else {
                    u16* dst = (bn0 >= 3072) ? Kh : Qh;
                    int cc = (bn0 >= 3072) ? c - 3072 : c;
                    int b = row >> 11, s = row & 2047;
                    int h, d;
                    if (cc < 2048) { h = cc >> 7; d = cc & 127; }
                    else { int mm = cc - 2048; h = mm >> 6; d = 128 + (mm & 63); }
                    dst[(((size_t)b * 16 + h) * 2048 + s) * 192 + d] = f2bf(v);
                }
            }
}

// ---------------- GEMM: C[M][N] = A[M][K] * Bt[N][K]^T  (bf16 in, fp32 out) ----
__global__ __launch_bounds__(256) void gemm_bt_f32(const u16* __restrict__ A,
                                                   const u16* __restrict__ Bt,
                                                   float* __restrict__ C,
                                                   int M, int N, int K) {
    __shared__ __align__(16) u16 As[128 * 64];
    __shared__ __align__(16) u16 Bs[128 * 64];
    const int tid = threadIdx.x, lane = tid & 63, wid = tid >> 6;
    const int l15 = lane & 15, l4 = lane >> 4;
    const int bm0 = blockIdx.y << 7, bn0 = blockIdx.x << 7;
    const int wr = wid >> 1, wc = wid & 1;
    f32x4 acc[4][4] = {};
    const int nk = K >> 6;
    for (int t = 0; t < nk; ++t) {
        const int k0 = t << 6;
#pragma unroll
        for (int i = 0; i < 4; ++i) {
            int c = i * 256 + tid;
            int row = c >> 3, c8 = c & 7;
            GLDS16(A + (size_t)(bm0 + row) * K + k0 + c8 * 8,
                   (char*)As + (i * 256 + wid * 64) * 16);
        }
#pragma unroll
        for (int i = 0; i < 4; ++i) {
            int c = i * 256 + tid;
            int row = c >> 3, c8 = c & 7;
            GLDS16(Bt + (size_t)(bn0 + row) * K + k0 + c8 * 8,
                   (char*)Bs + (i * 256 + wid * 64) * 16);
        }
        __syncthreads();
#pragma unroll
        for (int kk = 0; kk < 64; kk += 32) {
            s16x8 af[4], bfr[4];
#pragma unroll
            for (int m = 0; m < 4; ++m)
                af[m] = *(const s16x8*)(As + (wr * 64 + m * 16 + l15) * 64 + kk + l4 * 8);
#pragma unroll
            for (int n = 0; n < 4; ++n)
                bfr[n] = *(const s16x8*)(Bs + (wc * 64 + n * 16 + l15) * 64 + kk + l4 * 8);
#pragma unroll
            for (int m = 0; m < 4; ++m)
#pragma unroll
                for (int n = 0; n < 4; ++n)
                    acc[m][n] = __builtin_amdgcn_mfma_f32_16x16x32_bf16(af[m], bfr[n],
                                                                        acc[m][n], 0, 0, 0);
        }
        __syncthreads();
    }
#pragma unroll
    for (int m = 0; m < 4; ++m)
#pragma unroll
        for (int n = 0; n < 4; ++n)
#pragma unroll
            for (int r = 0; r < 4; ++r) {
                int row = bm0 + wr * 64 + m * 16 + l4 * 4 + r;
                int col = bn0 + wc * 64 + n * 16 + l15;
                C[(size_t)row * N + col] = acc[m][n][r];
            }
}

// ---------------- RoPE in-place on BOTH Q and K [BH][S][192], d in [128,192) ----
__global__ __launch_bounds__(256) void rope2(u16* __restrict__ Qh,
                                             u16* __restrict__ Kh,
                                             const float* __restrict__ freqs) {
    int idx = blockIdx.x * 256 + threadIdx.x;
    int j = idx & 31, s = (idx >> 5) & 2047, u = idx >> 16;  // u in [0,64)
    u16* T = (u < 32) ? Qh : Kh;
    int bh = u & 31;
    float ang = freqs[s * 32 + j];
    float c = cosf(ang), sn = sinf(ang);
    u32* p = (u32*)(T + ((size_t)bh * 2048 + s) * 192 + 128) + j;
    u32 v = *p;
    float t0 = bf2f((u16)(v & 0xffff)), t1 = bf2f((u16)(v >> 16));
    float o0 = t0 * c - t1 * sn;
    float o1 = t0 * sn + t1 * c;
    *p = (u32)f2bf(o0) | ((u32)f2bf(o1) << 16);
}

// ---------------- V [b][s][h*128+d] -> Vt [bh][d][s] ----------------
__global__ __launch_bounds__(256) void vtrans(const u16* __restrict__ Vn,
                                              u16* __restrict__ Vt) {
    __shared__ u16 tile[32][33];
    int s0 = blockIdx.x * 32, d0 = blockIdx.y * 32, bh = blockIdx.z;
    int b = bh >> 4, h = bh & 15;
    int tx = threadIdx.x & 31, ty = threadIdx.x >> 5;
#pragma unroll
    for (int i = 0; i < 4; ++i) {
        int s = ty + i * 8;
        tile[s][tx] = Vn[((size_t)b * 2048 + s0 + s) * 2048 + h * 128 + d0 + tx];
    }
    __syncthreads();
#pragma unroll
    for (int i = 0; i < 4; ++i) {
        int d = ty + i * 8;
        Vt[((size_t)bh * 128 + d0 + d) * 2048 + s0 + tx] = tile[tx][d];
    }
}

// ---------------- causal flash attention v3, K-only ring-2 (80 KB, 2 blk/CU) ----
// BALANCED PAIRING (R8): ids 0-255 -> qt 15..8, ids 256-511 -> qt 0..7.
// With round-robin id->CU assignment, CU c gets qt pair (15-j, j) -> uniform
// 34 tiles/CU (was 48..20 with heavy-first for all ids).
__global__ __launch_bounds__(256) void attn_fwd3(const u16* __restrict__ Qh,
                                                 const u16* __restrict__ Kh,
                                                 const u16* __restrict__ Vt,
                                                 u16* __restrict__ AO) {
    __shared__ __align__(16) u16 Ks[2][64 * 192];   // 48 KB
    __shared__ __align__(16) u16 Vs[128 * 64];      // 16 KB  [d][s]
    __shared__ __align__(16) u16 Ps[4][32 * 64];    // 16 KB  per-wave [qrow][k]
    const int tid = threadIdx.x, lane = tid & 63, wid = tid >> 6;
    const int l15 = lane & 15, l4 = lane >> 4;
    const int id = blockIdx.x;
    const int bh = id & 31;
    const int j = (id & 255) >> 5;
    const int qt = (id < 256) ? (15 - j) : j;   // balanced pairing
    const int q0 = qt << 7;
    const u16* Qb = Qh + ((size_t)bh * 2048 + q0 + wid * 32) * 192;
    const u16* Kb = Kh + (size_t)bh * 2048 * 192;
    const u16* Vb = Vt + (size_t)bh * 128 * 2048;

    auto stageK = [&](int t, int buf) {
        const int k0 = t << 6;
#pragma unroll
        for (int i = 0; i < 6; ++i) {
            int c = i * 256 + tid;
            int row = (u32)c / 24u, cc = c - row * 24;
            int cs = (cc & 24) | ((cc ^ row) & 7);
            GLDS16(Kb + (size_t)(k0 + row) * 192 + cs * 8,
                   (char*)Ks[buf] + (i * 256 + wid * 64) * 16);
        }
    };
    auto stageV = [&](int t) {
        const int k0 = t << 6;
#pragma unroll
        for (int i = 0; i < 4; ++i) {
            int c = i * 256 + tid;
            int d = c >> 3, cc = c & 7;
            int cs = cc ^ (d & 7);
            GLDS16(Vb + (size_t)d * 2048 + k0 + cs * 8,
                   (char*)Vs + (i * 256 + wid * 64) * 16);
        }
    };

    s16x8 aq[2][6];
#pragma unroll
    for (int qg = 0; qg < 2; ++qg)
#pragma unroll
        for (int dk = 0; dk < 6; ++dk)
            aq[qg][dk] = *(const s16x8*)(Qb + (size_t)(qg * 16 + l15) * 192 + dk * 32 + l4 * 8);

    f32x4 acc[2][8] = {};
    float mrow[2][4], lpart[2][4];
#pragma unroll
    for (int qg = 0; qg < 2; ++qg)
#pragma unroll
        for (int r = 0; r < 4; ++r) { mrow[qg][r] = -1e30f; lpart[qg][r] = 0.f; }
    const float scale = 0.07216878364870322f;  // 1/sqrt(192)

    const int ntile = (qt + 1) << 1;
    stageK(0, 0);
    for (int t = 0; t < ntile; ++t) {
        const int cur = t & 1;
        const int k0 = t << 6;
        const bool pf = (t + 1 < ntile);
        stageV(t);
        if (pf) stageK(t + 1, cur ^ 1);
        if (pf) { VMCNT10; } else { VMCNT4; }   // retire K(t)
        SBAR;
        __builtin_amdgcn_s_barrier();
        SBAR;

        const bool live = (q0 + wid * 32 + 31 >= k0);
        if (live) {
            const u16* Kc = Ks[cur];
            f32x4 sc[2][4];
#pragma unroll
            for (int qg = 0; qg < 2; ++qg)
#pragma unroll
                for (int kg = 0; kg < 4; ++kg) sc[qg][kg] = f32x4{0.f, 0.f, 0.f, 0.f};
            __builtin_amdgcn_s_setprio(1);
#pragma unroll
            for (int dk = 0; dk < 6; ++dk) {
                s16x8 bk[4];
#pragma unroll
                for (int kg = 0; kg < 4; ++kg) {
                    int row = kg * 16 + l15;
                    int byt = (row * 384 + dk * 64 + l4 * 16) ^ ((row & 7) << 4);
                    bk[kg] = *(const s16x8*)((const char*)Kc + byt);
                }
#pragma unroll
                for (int qg = 0; qg < 2; ++qg)
#pragma unroll
                    for (int kg = 0; kg < 4; ++kg)
                        sc[qg][kg] = __builtin_amdgcn_mfma_f32_16x16x32_bf16(
                            aq[qg][dk], bk[kg], sc[qg][kg], 0, 0, 0);
            }
            __builtin_amdgcn_s_setprio(0);

            u16* Pw = Ps[wid];
#pragma unroll
            for (int qg = 0; qg < 2; ++qg) {
                const int qrow = q0 + wid * 32 + qg * 16 + l4 * 4;
                const bool domask = (k0 + 63 > qrow);
                float p[4][4], tm[4];
#pragma unroll
                for (int r = 0; r < 4; ++r) tm[r] = -1e30f;
#pragma unroll
                for (int kg = 0; kg < 4; ++kg)
#pragma unroll
                    for (int r = 0; r < 4; ++r) {
                        float v = sc[qg][kg][r] * scale;
                        if (domask && (k0 + kg * 16 + l15 > qrow + r)) v = -1e30f;
                        p[kg][r] = v;
                        tm[r] = fmaxf(tm[r], v);
                    }
#pragma unroll
                for (int off = 1; off < 16; off <<= 1)
#pragma unroll
                    for (int r = 0; r < 4; ++r)
                        tm[r] = fmaxf(tm[r], __shfl_xor(tm[r], off, 64));
                float mn[4];
                bool resc = false;
#pragma unroll
                for (int r = 0; r < 4; ++r) {
                    mn[r] = (tm[r] <= mrow[qg][r] + 8.f) ? mrow[qg][r] : tm[r];
                    resc |= (mn[r] > mrow[qg][r]);
                }
                if (__any(resc)) {
#pragma unroll
                    for (int r = 0; r < 4; ++r) {
                        float scl = __expf(mrow[qg][r] - mn[r]);
                        mrow[qg][r] = mn[r];
                        lpart[qg][r] *= scl;
#pragma unroll
                        for (int db = 0; db < 8; ++db) acc[qg][db][r] *= scl;
                    }
                }
#pragma unroll
                for (int kg = 0; kg < 4; ++kg)
#pragma unroll
                    for (int r = 0; r < 4; ++r) {
                        p[kg][r] = __expf(p[kg][r] - mrow[qg][r]);
                        lpart[qg][r] += p[kg][r];
                    }
#pragma unroll
                for (int kg = 0; kg < 4; ++kg)
#pragma unroll
                    for (int r = 0; r < 4; ++r) {
                        int row = qg * 16 + l4 * 4 + r;
                        int byt = ((row * 64 + kg * 16 + l15) * 2) ^ ((row & 7) << 4);
                        *(u16*)((char*)Pw + byt) = f2bf(p[kg][r]);
                    }
            }
        }

        if (pf) { VMCNT6; } else { VMCNT0; }   // retire V(t)
        SBAR;
        __builtin_amdgcn_s_barrier();
        SBAR;

        if (live) {
            u16* Pw = Ps[wid];
            __builtin_amdgcn_s_setprio(1);
#pragma unroll
            for (int kk = 0; kk < 2; ++kk) {
                s16x8 ap[2];
#pragma unroll
                for (int qg = 0; qg < 2; ++qg) {
                    int row = qg * 16 + l15;
                    int byt = ((row * 64 + kk * 32 + l4 * 8) * 2) ^ ((row & 7) << 4);
                    ap[qg] = *(const s16x8*)((const char*)Pw + byt);
                }
#pragma unroll
                for (int db = 0; db < 8; ++db) {
                    int row = db * 16 + l15;
                    int byt = (row * 128 + kk * 64 + l4 * 16) ^ ((row & 7) << 4);
                    s16x8 bv = *(const s16x8*)((const char*)Vs + byt);
#pragma unroll
                    for (int qg = 0; qg < 2; ++qg)
                        acc[qg][db] = __builtin_amdgcn_mfma_f32_16x16x32_bf16(
                            ap[qg], bv, acc[qg][db], 0, 0, 0);
                }
            }
            __builtin_amdgcn_s_setprio(0);
        }
        SBAR;
        __builtin_amdgcn_s_barrier();
        SBAR;
    }

#pragma unroll
    for (int off = 1; off < 16; off <<= 1)
#pragma unroll
        for (int qg = 0; qg < 2; ++qg)
#pragma unroll
            for (int r = 0; r < 4; ++r)
                lpart[qg][r] += __shfl_xor(lpart[qg][r], off, 64);

    const int b = bh >> 4, h = bh & 15;
#pragma unroll
    for (int qg = 0; qg < 2; ++qg) {
        float inv[4];
#pragma unroll
        for (int r = 0; r < 4; ++r) inv[r] = 1.f / lpart[qg][r];
#pragma unroll
        for (int db = 0; db < 8; ++db)
#pragma unroll
            for (int r = 0; r < 4; ++r) {
                int row = q0 + wid * 32 + qg * 16 + l4 * 4 + r;
                AO[((size_t)b * 2048 + row) * 2048 + h * 128 + db * 16 + l15] =
                    f2bf(acc[qg][db][r] * inv[r]);
            }
    }
}

extern "C" void kernel_launch(void* const* d_in, const int* in_sizes, int n_in,
                              void* d_out, int out_size, void* d_ws, size_t ws_size,
                              hipStream_t stream) {
    const float* x     = (const float*)d_in[0];
    const float* freqs = (const float*)d_in[2];
    const float* wq    = (const float*)d_in[4];
    const float* wk    = (const float*)d_in[5];
    const float* wv    = (const float*)d_in[6];
    const float* wo    = (const float*)d_in[7];
    float* out = (float*)d_out;

    char* ws = (char*)d_ws;
    u16* xb   = (u16*)(ws + 0);           // 16 MB  x bf16 [4096][2048]
    u16* WT   = (u16*)(ws + 16777216);    // 32 MB  [8192][2048]: wq^T|wk^T|wv^T
    u16* woT  = (u16*)(ws + 50331648);    //  8 MB  [2048][2048]
    u16* Qh   = (u16*)(ws + 58720256);    // 24 MB  [BH][S][192]
    u16* Kh   = (u16*)(ws + 83886080);    // 24 MB
    u16* Vn   = (u16*)(ws + 109051904);   // 16 MB  [4096][2048]
    u16* Vt   = (u16*)(ws + 125829120);   // 16 MB  [BH][128][S]
    u16* AO   = (u16*)(ws + 142606336);   // 16 MB  [4096][2048]

    prep<<<13312, 256, 0, stream>>>((const float4*)x, (ushort4*)xb,
                                    wq, wk, wv, wo, WT, woT);
    gemm_qkv<<<dim3(512), 512, 0, stream>>>(xb, WT, Qh, Kh, Vn);
    rope2<<<16384, 256, 0, stream>>>(Qh, Kh, freqs);
    vtrans<<<dim3(64, 4, 32), 256, 0, stream>>>(Vn, Vt);
    attn_fwd3<<<dim3(512), 256, 0, stream>>>(Qh, Kh, Vt, AO);
    gemm_bt_f32<<<dim3(16, 32), 256, 0, stream>>>(AO, woT, out, 4096, 2048, 2048);
}

// Round 9
// 340.033 us; speedup vs baseline: 1.1273x; 1.1273x over previous
//
#include <hip/hip_runtime.h>
#include <hip/hip_bf16.h>

typedef __attribute__((ext_vector_type(4))) float f32x4;
typedef __attribute__((ext_vector_type(8))) short s16x8;
typedef unsigned int u32;
typedef unsigned short u16;

#define GLDS16(gp, lp) __builtin_amdgcn_global_load_lds(                         \
    (const __attribute__((address_space(1))) u32*)(gp),                          \
    (__attribute__((address_space(3))) u32*)(lp), 16, 0, 0)
#define VMCNT4 asm volatile("s_waitcnt vmcnt(4)" ::: "memory")
#define VMCNT0 asm volatile("s_waitcnt vmcnt(0)" ::: "memory")
#define LGKM8  asm volatile("s_waitcnt lgkmcnt(8)" ::: "memory")
#define LGKM0  asm volatile("s_waitcnt lgkmcnt(0)" ::: "memory")
#define SBAR   __builtin_amdgcn_sched_barrier(0)

__device__ __forceinline__ u16 f2bf(float f) {
    u32 u = __builtin_bit_cast(u32, f);
    u32 r = (u + 0x7FFFu + ((u >> 16) & 1u)) >> 16;
    return (u16)r;
}
__device__ __forceinline__ float bf2f(u16 h) {
    u32 u = ((u32)h) << 16;
    return __builtin_bit_cast(float, u);
}

// ---------------- fused prep: x cast + 4 weight transposes, one launch ----------
// blocks [0,8192): conv f32->bf16 of x (float4)
// blocks [8192,13312): wtrans 32k x 128n tiles, float4 reads
__global__ __launch_bounds__(256) void prep(const float4* __restrict__ x,
                                            ushort4* __restrict__ xb4,
                                            const float* __restrict__ wq,
                                            const float* __restrict__ wk,
                                            const float* __restrict__ wv,
                                            const float* __restrict__ wo,
                                            u16* __restrict__ WT,
                                            u16* __restrict__ woT) {
    __shared__ float tile[32][132];  // pad 4: benign 4-way on scalar access
    int bid = blockIdx.x;
    if (bid < 8192) {
        int i = bid * 256 + threadIdx.x;
        float4 v = x[i];
        ushort4 o;
        o.x = f2bf(v.x); o.y = f2bf(v.y); o.z = f2bf(v.z); o.w = f2bf(v.w);
        xb4[i] = o;
        return;
    }
    bid -= 8192;
    const float* src;
    u16* dst;
    int N, bx, by;
    if (bid < 1536)      { src = wq; dst = WT;                         N = 3072; bx = bid % 24; by = bid / 24; }
    else if (bid < 3072) { bid -= 1536; src = wk; dst = WT + (size_t)3072 * 2048; N = 3072; bx = bid % 24; by = bid / 24; }
    else if (bid < 4096) { bid -= 3072; src = wv; dst = WT + (size_t)6144 * 2048; N = 2048; bx = bid % 16; by = bid / 16; }
    else                 { bid -= 4096; src = wo; dst = woT;           N = 2048; bx = bid % 16; by = bid / 16; }
    int n0 = bx * 128, k0 = by * 32;
    int nf = threadIdx.x & 31, kr = threadIdx.x >> 5;  // 32 float4-cols x 8 rows
#pragma unroll
    for (int i = 0; i < 4; ++i) {
        int row = kr + i * 8;
        float4 v = *(const float4*)&src[(size_t)(k0 + row) * N + n0 + 4 * nf];
        tile[row][4 * nf + 0] = v.x;
        tile[row][4 * nf + 1] = v.y;
        tile[row][4 * nf + 2] = v.z;
        tile[row][4 * nf + 3] = v.w;
    }
    __syncthreads();
    int kk = threadIdx.x & 31, nr0 = threadIdx.x >> 5;  // 32 k x 8 n-rows/pass
#pragma unroll
    for (int i = 0; i < 16; ++i) {
        int n = nr0 + i * 8;
        dst[(size_t)(n0 + n) * 2048 + k0 + kk] = f2bf(tile[kk][n]);
    }
}

// ---------------- fused QKV GEMM: m201 8-phase template, BK=64, 2x2-half dbuf ----
// Epilogue: head-pack Q/K into [BH][S][192], V plain [4096][2048].
// NOTE (R4): no transcendentals here. NOTE (R6): no scattered V-transpose here.
__global__ __launch_bounds__(512, 2) void gemm_qkv(const u16* __restrict__ A,
                                                   const u16* __restrict__ W,
                                                   u16* __restrict__ Qh,
                                                   u16* __restrict__ Kh,
                                                   u16* __restrict__ Vn) {
    __shared__ __align__(16) u16 S[2][2][2][128 * 64];  // [mat][dbuf][half] 128 KiB
    const int tid = threadIdx.x, lane = tid & 63, wid = tid >> 6;
    const int l15 = lane & 15, l4 = lane >> 4;
    const int id = blockIdx.x;
    const int nt = ((id & 7) << 2) + ((id >> 3) & 3);
    const int mt = id >> 5;
    const int bm0 = mt << 8, bn0 = nt << 8;
    const int wr = wid >> 2, wc = wid & 3;  // 2M x 4N
    f32x4 acc[8][4] = {};

    auto stageH = [&](int mat, int tt, int h) {
        const int kc = tt << 6, p = tt & 1;
        const u16* G = mat ? W : A;
        const int rbase = (mat ? bn0 : bm0) + (h << 7);
        u16* Ld = S[mat][p][h];
#pragma unroll
        for (int j = 0; j < 2; ++j) {
            int c = j * 512 + tid;
            int row = c >> 3, ch = c & 7;
            int cs = ch ^ (row & 7);
            GLDS16(G + (size_t)(rbase + row) * 2048 + kc + cs * 8,
                   (char*)Ld + (j * 512 + wid * 64) * 16);
        }
    };

    s16x8 af[2][2], bfr[4][2];

#define RDA(P, I)                                                              \
    _Pragma("unroll") for (int mm = 0; mm < 2; ++mm)                           \
    _Pragma("unroll") for (int kk = 0; kk < 2; ++kk) {                         \
        int r7 = ((I) * 2 + mm) * 16 + l15;                                    \
        int byt = r7 * 128 + (((kk * 4 + l4) ^ (r7 & 7)) << 4);                \
        af[mm][kk] = *(const s16x8*)((const char*)S[0][P][wr] + byt);          \
    }
#define RDB(P)                                                                 \
    _Pragma("unroll") for (int n = 0; n < 4; ++n)                              \
    _Pragma("unroll") for (int kk = 0; kk < 2; ++kk) {                         \
        int r7 = (wc & 1) * 64 + n * 16 + l15;                                 \
        int byt = r7 * 128 + (((kk * 4 + l4) ^ (r7 & 7)) << 4);                \
        bfr[n][kk] = *(const s16x8*)((const char*)S[1][P][wc >> 1] + byt);     \
    }
#define MF(I)                                                                  \
    __builtin_amdgcn_s_setprio(1);                                             \
    _Pragma("unroll") for (int mm = 0; mm < 2; ++mm)                           \
    _Pragma("unroll") for (int n = 0; n < 4; ++n)                              \
    _Pragma("unroll") for (int kk = 0; kk < 2; ++kk)                           \
        acc[(I) * 2 + mm][n] = __builtin_amdgcn_mfma_f32_16x16x32_bf16(        \
            af[mm][kk], bfr[n][kk], acc[(I) * 2 + mm][n], 0, 0, 0);            \
    __builtin_amdgcn_s_setprio(0);

    stageH(0, 0, 0); stageH(0, 0, 1); stageH(1, 0, 0); stageH(1, 0, 1);
    stageH(0, 1, 0); stageH(0, 1, 1);
    VMCNT4;
    __builtin_amdgcn_s_barrier();
    SBAR;

    for (int t = 0; t < 32; ++t) {
        const int p = t & 1;
        RDB(p); RDA(p, 0);
        if (t == 0) stageH(1, 1, 0);
        else if (t < 31) stageH(0, t + 1, 0);
        LGKM8; SBAR;
        __builtin_amdgcn_s_barrier();
        LGKM0; SBAR;
        MF(0); SBAR;
        __builtin_amdgcn_s_barrier();
        RDA(p, 1);
        if (t == 0) stageH(1, 1, 1);
        else if (t < 31) stageH(0, t + 1, 1);
        __builtin_amdgcn_s_barrier();
        LGKM0; SBAR;
        MF(1); SBAR;
        __builtin_amdgcn_s_barrier();
        RDA(p, 2);
        if (t < 30) stageH(1, t + 2, 0);
        __builtin_amdgcn_s_barrier();
        LGKM0; SBAR;
        MF(2); SBAR;
        __builtin_amdgcn_s_barrier();
        RDA(p, 3);
        if (t < 30) stageH(1, t + 2, 1);
        __builtin_amdgcn_s_barrier();
        LGKM0; SBAR;
        MF(3); SBAR;
        if (t < 31) {
            if (t < 30) { VMCNT4; } else { VMCNT0; }
            SBAR;
        }
        __builtin_amdgcn_s_barrier();
    }
#undef RDA
#undef RDB
#undef MF

    // epilogue
#pragma unroll
    for (int m = 0; m < 8; ++m)
#pragma unroll
        for (int n = 0; n < 4; ++n)
#pragma unroll
            for (int r = 0; r < 4; ++r) {
                int row = bm0 + wr * 128 + m * 16 + l4 * 4 + r;
                int c = bn0 + wc * 64 + n * 16 + l15;
                float v = acc[m][n][r];
                if (bn0 >= 6144) {
                    Vn[(size_t)row * 2048 + (c - 6144)] = f2bf(v);
                } else {
                    u16* dst = (bn0 >= 3072) ? Kh : Qh;
                    int cc = (bn0 >= 3072) ? c - 3072 : c;
                    int b = row >> 11, s = row & 2047;
                    int h, d;
                    if (cc < 2048) { h = cc >> 7; d = cc & 127; }
                    else { int mm = cc - 2048; h = mm >> 6; d = 128 + (mm & 63); }
                    dst[(((size_t)b * 16 + h) * 2048 + s) * 192 + d] = f2bf(v);
                }
            }
}

// ---------------- GEMM: C[M][N] = A[M][K] * Bt[N][K]^T  (bf16 in, fp32 out) ----
__global__ __launch_bounds__(256) void gemm_bt_f32(const u16* __restrict__ A,
                                                   const u16* __restrict__ Bt,
                                                   float* __restrict__ C,
                                                   int M, int N, int K) {
    __shared__ __align__(16) u16 As[128 * 64];
    __shared__ __align__(16) u16 Bs[128 * 64];
    const int tid = threadIdx.x, lane = tid & 63, wid = tid >> 6;
    const int l15 = lane & 15, l4 = lane >> 4;
    const int bm0 = blockIdx.y << 7, bn0 = blockIdx.x << 7;
    const int wr = wid >> 1, wc = wid & 1;
    f32x4 acc[4][4] = {};
    const int nk = K >> 6;
    for (int t = 0; t < nk; ++t) {
        const int k0 = t << 6;
#pragma unroll
        for (int i = 0; i < 4; ++i) {
            int c = i * 256 + tid;
            int row = c >> 3, c8 = c & 7;
            GLDS16(A + (size_t)(bm0 + row) * K + k0 + c8 * 8,
                   (char*)As + (i * 256 + wid * 64) * 16);
        }
#pragma unroll
        for (int i = 0; i < 4; ++i) {
            int c = i * 256 + tid;
            int row = c >> 3, c8 = c & 7;
            GLDS16(Bt + (size_t)(bn0 + row) * K + k0 + c8 * 8,
                   (char*)Bs + (i * 256 + wid * 64) * 16);
        }
        __syncthreads();
#pragma unroll
        for (int kk = 0; kk < 64; kk += 32) {
            s16x8 af[4], bfr[4];
#pragma unroll
            for (int m = 0; m < 4; ++m)
                af[m] = *(const s16x8*)(As + (wr * 64 + m * 16 + l15) * 64 + kk + l4 * 8);
#pragma unroll
            for (int n = 0; n < 4; ++n)
                bfr[n] = *(const s16x8*)(Bs + (wc * 64 + n * 16 + l15) * 64 + kk + l4 * 8);
#pragma unroll
            for (int m = 0; m < 4; ++m)
#pragma unroll
                for (int n = 0; n < 4; ++n)
                    acc[m][n] = __builtin_amdgcn_mfma_f32_16x16x32_bf16(af[m], bfr[n],
                                                                        acc[m][n], 0, 0, 0);
        }
        __syncthreads();
    }
#pragma unroll
    for (int m = 0; m < 4; ++m)
#pragma unroll
        for (int n = 0; n < 4; ++n)
#pragma unroll
            for (int r = 0; r < 4; ++r) {
                int row = bm0 + wr * 64 + m * 16 + l4 * 4 + r;
                int col = bn0 + wc * 64 + n * 16 + l15;
                C[(size_t)row * N + col] = acc[m][n][r];
            }
}

// ---------------- RoPE in-place on BOTH Q and K per thread (shared cos/sin) ------
__global__ __launch_bounds__(256) void rope_qk(u16* __restrict__ Qh,
                                               u16* __restrict__ Kh,
                                               const float* __restrict__ freqs) {
    int idx = blockIdx.x * 256 + threadIdx.x;   // 32bh x 2048s x 32j
    int j = idx & 31, s = (idx >> 5) & 2047, bh = idx >> 16;
    float ang = freqs[s * 32 + j];
    float c = cosf(ang), sn = sinf(ang);
    size_t off = ((size_t)bh * 2048 + s) * 192 + 128;
    u32* pq = (u32*)(Qh + off) + j;
    u32* pk = (u32*)(Kh + off) + j;
    u32 vq = *pq, vk = *pk;
    float q0 = bf2f((u16)(vq & 0xffff)), q1 = bf2f((u16)(vq >> 16));
    float k0 = bf2f((u16)(vk & 0xffff)), k1 = bf2f((u16)(vk >> 16));
    *pq = (u32)f2bf(q0 * c - q1 * sn) | ((u32)f2bf(q0 * sn + q1 * c) << 16);
    *pk = (u32)f2bf(k0 * c - k1 * sn) | ((u32)f2bf(k0 * sn + k1 * c) << 16);
}

// ---------------- V [b][s][h*128+d] -> Vt [bh][d][s] ----------------
__global__ __launch_bounds__(256) void vtrans(const u16* __restrict__ Vn,
                                              u16* __restrict__ Vt) {
    __shared__ u16 tile[32][33];
    int s0 = blockIdx.x * 32, d0 = blockIdx.y * 32, bh = blockIdx.z;
    int b = bh >> 4, h = bh & 15;
    int tx = threadIdx.x & 31, ty = threadIdx.x >> 5;
#pragma unroll
    for (int i = 0; i < 4; ++i) {
        int s = ty + i * 8;
        tile[s][tx] = Vn[((size_t)b * 2048 + s0 + s) * 2048 + h * 128 + d0 + tx];
    }
    __syncthreads();
#pragma unroll
    for (int i = 0; i < 4; ++i) {
        int d = ty + i * 8;
        Vt[((size_t)bh * 128 + d0 + d) * 2048 + s0 + tx] = tile[tx][d];
    }
}

// ---------------- causal flash attention v3 (R5 proven config) ----------------
// Single-buffer stage + __syncthreads; heavy-first qt = 15-(id>>5) — this is an
// LPT order under the HW's greedy block dispatch (R8 post-mortem: do NOT
// replace with static pairings; reordering cost +34us).
__global__ __launch_bounds__(256) void attn_fwd3(const u16* __restrict__ Qh,
                                                 const u16* __restrict__ Kh,
                                                 const u16* __restrict__ Vt,
                                                 u16* __restrict__ AO) {
    __shared__ __align__(16) u16 Ks[64 * 192];   // 24 KB
    __shared__ __align__(16) u16 Vs[128 * 64];   // 16 KB  [d][s]
    __shared__ __align__(16) u16 Ps[4][32 * 64]; // 16 KB  per-wave [qrow][k]
    const int tid = threadIdx.x, lane = tid & 63, wid = tid >> 6;
    const int l15 = lane & 15, l4 = lane >> 4;
    const int id = blockIdx.x;
    const int bh = id & 31;
    const int qt = 15 - (id >> 5);      // heavy-first (LPT under greedy dispatch)
    const int q0 = qt << 7;
    const u16* Qb = Qh + ((size_t)bh * 2048 + q0 + wid * 32) * 192;
    const u16* Kb = Kh + (size_t)bh * 2048 * 192;
    const u16* Vb = Vt + (size_t)bh * 128 * 2048;

    s16x8 aq[2][6];
#pragma unroll
    for (int qg = 0; qg < 2; ++qg)
#pragma unroll
        for (int dk = 0; dk < 6; ++dk)
            aq[qg][dk] = *(const s16x8*)(Qb + (size_t)(qg * 16 + l15) * 192 + dk * 32 + l4 * 8);

    f32x4 acc[2][8] = {};
    float mrow[2][4], lpart[2][4];
#pragma unroll
    for (int qg = 0; qg < 2; ++qg)
#pragma unroll
        for (int r = 0; r < 4; ++r) { mrow[qg][r] = -1e30f; lpart[qg][r] = 0.f; }
    const float scale = 0.07216878364870322f;  // 1/sqrt(192)

    const int ntile = (qt + 1) << 1;
    for (int t = 0; t < ntile; ++t) {
        const int k0 = t << 6;
#pragma unroll
        for (int i = 0; i < 6; ++i) {
            int c = i * 256 + tid;
            int row = (u32)c / 24u, cc = c - row * 24;
            int cs = (cc & 24) | ((cc ^ row) & 7);
            GLDS16(Kb + (size_t)(k0 + row) * 192 + cs * 8,
                   (char*)Ks + (i * 256 + wid * 64) * 16);
        }
#pragma unroll
        for (int i = 0; i < 4; ++i) {
            int c = i * 256 + tid;
            int d = c >> 3, cc = c & 7;
            int cs = cc ^ (d & 7);
            GLDS16(Vb + (size_t)d * 2048 + k0 + cs * 8,
                   (char*)Vs + (i * 256 + wid * 64) * 16);
        }
        __syncthreads();

        if (q0 + wid * 32 + 31 >= k0) {
            f32x4 sc[2][4];
#pragma unroll
            for (int qg = 0; qg < 2; ++qg)
#pragma unroll
                for (int kg = 0; kg < 4; ++kg) sc[qg][kg] = f32x4{0.f, 0.f, 0.f, 0.f};
            __builtin_amdgcn_s_setprio(1);
#pragma unroll
            for (int dk = 0; dk < 6; ++dk) {
                s16x8 bk[4];
#pragma unroll
                for (int kg = 0; kg < 4; ++kg) {
                    int row = kg * 16 + l15;
                    int byt = (row * 384 + dk * 64 + l4 * 16) ^ ((row & 7) << 4);
                    bk[kg] = *(const s16x8*)((const char*)Ks + byt);
                }
#pragma unroll
                for (int qg = 0; qg < 2; ++qg)
#pragma unroll
                    for (int kg = 0; kg < 4; ++kg)
                        sc[qg][kg] = __builtin_amdgcn_mfma_f32_16x16x32_bf16(
                            aq[qg][dk], bk[kg], sc[qg][kg], 0, 0, 0);
            }
            __builtin_amdgcn_s_setprio(0);

            u16* Pw = Ps[wid];
#pragma unroll
            for (int qg = 0; qg < 2; ++qg) {
                const int qrow = q0 + wid * 32 + qg * 16 + l4 * 4;
                const bool domask = (k0 + 63 > qrow);
                float p[4][4], tm[4];
#pragma unroll
                for (int r = 0; r < 4; ++r) tm[r] = -1e30f;
#pragma unroll
                for (int kg = 0; kg < 4; ++kg)
#pragma unroll
                    for (int r = 0; r < 4; ++r) {
                        float v = sc[qg][kg][r] * scale;
                        if (domask && (k0 + kg * 16 + l15 > qrow + r)) v = -1e30f;
                        p[kg][r] = v;
                        tm[r] = fmaxf(tm[r], v);
                    }
#pragma unroll
                for (int off = 1; off < 16; off <<= 1)
#pragma unroll
                    for (int r = 0; r < 4; ++r)
                        tm[r] = fmaxf(tm[r], __shfl_xor(tm[r], off, 64));
                float mn[4];
                bool resc = false;
#pragma unroll
                for (int r = 0; r < 4; ++r) {
                    mn[r] = (tm[r] <= mrow[qg][r] + 8.f) ? mrow[qg][r] : tm[r];
                    resc |= (mn[r] > mrow[qg][r]);
                }
                if (__any(resc)) {
#pragma unroll
                    for (int r = 0; r < 4; ++r) {
                        float scl = __expf(mrow[qg][r] - mn[r]);
                        mrow[qg][r] = mn[r];
                        lpart[qg][r] *= scl;
#pragma unroll
                        for (int db = 0; db < 8; ++db) acc[qg][db][r] *= scl;
                    }
                }
#pragma unroll
                for (int kg = 0; kg < 4; ++kg)
#pragma unroll
                    for (int r = 0; r < 4; ++r) {
                        p[kg][r] = __expf(p[kg][r] - mrow[qg][r]);
                        lpart[qg][r] += p[kg][r];
                    }
#pragma unroll
                for (int kg = 0; kg < 4; ++kg)
#pragma unroll
                    for (int r = 0; r < 4; ++r) {
                        int row = qg * 16 + l4 * 4 + r;
                        int byt = ((row * 64 + kg * 16 + l15) * 2) ^ ((row & 7) << 4);
                        *(u16*)((char*)Pw + byt) = f2bf(p[kg][r]);
                    }
            }

            __builtin_amdgcn_s_setprio(1);
#pragma unroll
            for (int kk = 0; kk < 2; ++kk) {
                s16x8 ap[2];
#pragma unroll
                for (int qg = 0; qg < 2; ++qg) {
                    int row = qg * 16 + l15;
                    int byt = ((row * 64 + kk * 32 + l4 * 8) * 2) ^ ((row & 7) << 4);
                    ap[qg] = *(const s16x8*)((const char*)Pw + byt);
                }
#pragma unroll
                for (int db = 0; db < 8; ++db) {
                    int row = db * 16 + l15;
                    int byt = (row * 128 + kk * 64 + l4 * 16) ^ ((row & 7) << 4);
                    s16x8 bv = *(const s16x8*)((const char*)Vs + byt);
#pragma unroll
                    for (int qg = 0; qg < 2; ++qg)
                        acc[qg][db] = __builtin_amdgcn_mfma_f32_16x16x32_bf16(
                            ap[qg], bv, acc[qg][db], 0, 0, 0);
                }
            }
            __builtin_amdgcn_s_setprio(0);
        }
        __syncthreads();
    }

#pragma unroll
    for (int off = 1; off < 16; off <<= 1)
#pragma unroll
        for (int qg = 0; qg < 2; ++qg)
#pragma unroll
            for (int r = 0; r < 4; ++r)
                lpart[qg][r] += __shfl_xor(lpart[qg][r], off, 64);

    const int b = bh >> 4, h = bh & 15;
#pragma unroll
    for (int qg = 0; qg < 2; ++qg) {
        float inv[4];
#pragma unroll
        for (int r = 0; r < 4; ++r) inv[r] = 1.f / lpart[qg][r];
#pragma unroll
        for (int db = 0; db < 8; ++db)
#pragma unroll
            for (int r = 0; r < 4; ++r) {
                int row = q0 + wid * 32 + qg * 16 + l4 * 4 + r;
                AO[((size_t)b * 2048 + row) * 2048 + h * 128 + db * 16 + l15] =
                    f2bf(acc[qg][db][r] * inv[r]);
            }
    }
}

extern "C" void kernel_launch(void* const* d_in, const int* in_sizes, int n_in,
                              void* d_out, int out_size, void* d_ws, size_t ws_size,
                              hipStream_t stream) {
    const float* x     = (const float*)d_in[0];
    const float* freqs = (const float*)d_in[2];
    const float* wq    = (const float*)d_in[4];
    const float* wk    = (const float*)d_in[5];
    const float* wv    = (const float*)d_in[6];
    const float* wo    = (const float*)d_in[7];
    float* out = (float*)d_out;

    char* ws = (char*)d_ws;
    u16* xb   = (u16*)(ws + 0);           // 16 MB  x bf16 [4096][2048]
    u16* WT   = (u16*)(ws + 16777216);    // 32 MB  [8192][2048]: wq^T|wk^T|wv^T
    u16* woT  = (u16*)(ws + 50331648);    //  8 MB  [2048][2048]
    u16* Qh   = (u16*)(ws + 58720256);    // 24 MB  [BH][S][192]
    u16* Kh   = (u16*)(ws + 83886080);    // 24 MB
    u16* Vn   = (u16*)(ws + 109051904);   // 16 MB  [4096][2048]
    u16* Vt   = (u16*)(ws + 125829120);   // 16 MB  [BH][128][S]
    u16* AO   = (u16*)(ws + 142606336);   // 16 MB  [4096][2048]

    prep<<<13312, 256, 0, stream>>>((const float4*)x, (ushort4*)xb,
                                    wq, wk, wv, wo, WT, woT);
    gemm_qkv<<<dim3(512), 512, 0, stream>>>(xb, WT, Qh, Kh, Vn);
    rope_qk<<<8192, 256, 0, stream>>>(Qh, Kh, freqs);
    vtrans<<<dim3(64, 4, 32), 256, 0, stream>>>(Vn, Vt);
    attn_fwd3<<<dim3(512), 256, 0, stream>>>(Qh, Kh, Vt, AO);
    gemm_bt_f32<<<dim3(16, 32), 256, 0, stream>>>(AO, woT, out, 4096, 2048, 2048);
}